// Round 2
// baseline (626.979 us; speedup 1.0000x reference)
//
#include <hip/hip_runtime.h>
#include <cstddef>

// Problem constants (fixed by the reference)
#define EPQ_SHIFT 11       // EPQ = 2048
#define KSEL 256

__device__ __forceinline__ unsigned enc_f(float f) {
  unsigned u = __float_as_uint(f);
  return (u & 0x80000000u) ? ~u : (u | 0x80000000u);
}
__device__ __forceinline__ float dec_f(unsigned k) {
  unsigned u = (k & 0x80000000u) ? (k ^ 0x80000000u) : ~k;
  return __uint_as_float(u);
}

// ---------------- K0: init output + segment buffers ----------------
__global__ void k0_init(float* __restrict__ out, float* __restrict__ segsum,
                        unsigned* __restrict__ segkey, int n) {
  int i = blockIdx.x * 256 + threadIdx.x;
  if (i < n) { out[i] = 0.f; segsum[i] = 0.f; segkey[i] = 0u; }
}

// ---------------- K1: M = Wq^T Wk (512x512), also Mt = M^T ----------------
__global__ __launch_bounds__(256) void k1_gemmM(const float* __restrict__ Wq,
                                                const float* __restrict__ Wk,
                                                float* __restrict__ M,
                                                float* __restrict__ Mt) {
  __shared__ float as[16][64];
  __shared__ float bs[16][64];
  int tid = threadIdx.x;
  int tx = tid & 15, ty = tid >> 4;
  int c1b = blockIdx.y * 64, c2b = blockIdx.x * 64;
  float acc[4][4] = {};
  for (int k0 = 0; k0 < 512; k0 += 16) {
#pragma unroll
    for (int l = 0; l < 4; ++l) {
      int lin = tid + l * 256;
      int kk = lin >> 6, c = lin & 63;
      as[kk][c] = Wq[(k0 + kk) * 512 + c1b + c];
      bs[kk][c] = Wk[(k0 + kk) * 512 + c2b + c];
    }
    __syncthreads();
#pragma unroll
    for (int kk = 0; kk < 16; ++kk) {
      float a[4], b[4];
#pragma unroll
      for (int m = 0; m < 4; ++m) a[m] = as[kk][ty * 4 + m];
#pragma unroll
      for (int n = 0; n < 4; ++n) b[n] = bs[kk][tx * 4 + n];
#pragma unroll
      for (int m = 0; m < 4; ++m)
#pragma unroll
        for (int n = 0; n < 4; ++n) acc[m][n] += a[m] * b[n];
    }
    __syncthreads();
  }
#pragma unroll
  for (int m = 0; m < 4; ++m)
#pragma unroll
    for (int n = 0; n < 4; ++n) {
      int c1 = c1b + ty * 4 + m, c2 = c2b + tx * 4 + n;
      M[c1 * 512 + c2] = acc[m][n];
      Mt[c2 * 512 + c1] = acc[m][n];
    }
}

// ---------------- K2m: merged node projections J0/J1/I1 ----------------
// lane = output dim d (split across 2 d-waves); matrix coeff streamed via
// stride-1 conflict-free LDS reads; hv rows fetched with wave-uniform
// addresses -> scalar loads (SGPR operand of v_fmac).
// p=0: J0[n][d] = sum_c M[d][c]     hv[n][c]  -> coeff = Mt[c*512 + d]
// p=1: J1[n][d] = sum_c M[128+d][c] hv[n][c]  -> coeff = Mt[c*512 + 128 + d]
// p=2: I1[n][d] = sum_c M[c][128+d] hv[n][c]  -> coeff = M [c*512 + 128 + d]
__global__ __launch_bounds__(256) void k2m_proj(const float* __restrict__ hv,
                                                const float* __restrict__ M,
                                                const float* __restrict__ Mt,
                                                float* __restrict__ J0,
                                                float* __restrict__ J1,
                                                float* __restrict__ I1, int N) {
  __shared__ float ms[64][128];
  const int tid = threadIdx.x;
  const int lane = tid & 63;
  const int wave = __builtin_amdgcn_readfirstlane(tid >> 6);
  const int dwave = wave & 1;   // which d-half this wave computes
  const int whalf = wave >> 1;  // which 32-node half this wave owns
  const int n0 = blockIdx.x * 64;
  const int d = dwave * 64 + lane;

  for (int p = 0; p < 3; ++p) {
    const float* base = (p == 0) ? Mt : (p == 1) ? (Mt + 128) : (M + 128);
    float* outp = (p == 0) ? J0 : (p == 1) ? J1 : I1;
    float acc[32];
#pragma unroll
    for (int i = 0; i < 32; ++i) acc[i] = 0.f;
    for (int ch = 0; ch < 2; ++ch) {
      __syncthreads();
      // stage ms[cc][dd] = base[(ch*64+cc)*512 + dd]  (both sides coalesced)
#pragma unroll
      for (int l = 0; l < 8; ++l) {
        int lin = tid + l * 256;
        int cc = lin >> 5, d4 = (lin & 31) * 4;
        *(float4*)&ms[cc][d4] = *(const float4*)&base[(size_t)(ch * 64 + cc) * 512 + d4];
      }
      __syncthreads();
      for (int c4 = 0; c4 < 16; ++c4) {
        // stride-1 across lanes: conflict-free
        float m0 = ms[c4 * 4 + 0][d];
        float m1 = ms[c4 * 4 + 1][d];
        float m2 = ms[c4 * 4 + 2][d];
        float m3 = ms[c4 * 4 + 3][d];
#pragma unroll
        for (int nch = 0; nch < 2; ++nch) {
#pragma unroll
          for (int n = 0; n < 16; ++n) {
            int gn = n0 + whalf * 32 + nch * 16 + n;  // wave-uniform
            gn = gn < N ? gn : N - 1;                 // keep loads in-bounds
            float4 h = *(const float4*)&hv[(size_t)gn * 128 + ch * 64 + c4 * 4];
            float a = acc[nch * 16 + n];
            a += h.x * m0;
            a += h.y * m1;
            a += h.z * m2;
            a += h.w * m3;
            acc[nch * 16 + n] = a;
          }
        }
      }
    }
#pragma unroll
    for (int i = 0; i < 32; ++i) {
      int gn = n0 + whalf * 32 + i;
      if (gn < N) outp[(size_t)gn * 128 + d] = acc[i];
    }
  }
}

// ---------------- K3: per-query vectors w,u,y and scalar c_b ----------------
__global__ __launch_bounds__(128) void k3_query(const float* __restrict__ qsrc,
                                                const float* __restrict__ qrel,
                                                const float* __restrict__ M,
                                                const float* __restrict__ Mt,
                                                float* __restrict__ wv,
                                                float* __restrict__ uv,
                                                float* __restrict__ yv,
                                                float* __restrict__ cb) {
  __shared__ float qcat[256];
  __shared__ float red[128];
  int b = blockIdx.x, d = threadIdx.x;
  qcat[d] = qsrc[b * 128 + d];
  qcat[128 + d] = qrel[b * 128 + d];
  __syncthreads();
  float w = 0.f, u = 0.f, y = 0.f, t1 = 0.f, t2 = 0.f;
  for (int c = 0; c < 256; ++c) {
    float q = qcat[c];
    size_t row = (size_t)(256 + c) * 512;
    w += Mt[row + d] * q;                        // M[d][256+c]
    u += M[row + d] * q;                         // M[256+c][d]
    y += (Mt[row + 128 + d] + M[row + 128 + d]) * q;  // x + v
    t1 += M[row + 256 + d] * q;                  // for c_b, col 256+d
    t2 += M[row + 384 + d] * q;                  // for c_b, col 384+d
  }
  wv[b * 128 + d] = w;
  uv[b * 128 + d] = u;
  yv[b * 128 + d] = y;
  red[d] = qcat[d] * t1 + qcat[128 + d] * t2;
  __syncthreads();
  for (int s = 64; s > 0; s >>= 1) {
    if (d < s) red[d] += red[d + s];
    __syncthreads();
  }
  if (d == 0) cb[b] = red[0];
}

// ---------------- K4m: edge_const[e] = rel^T M11 rel + rel.y_b + c_b ----
// Same SGPR-operand scheme as K2m. T[e][d] = sum_c M11[c][d] rel[e][c];
// then ec[e] = sum_d (T[e][d] + y_b[d]) * rel[e][d] + c_b.
// coeff = M[(128+c)*512 + 128 + d]  (contiguous in d)
__global__ __launch_bounds__(256) void k4m_edgeconst(const float* __restrict__ rel,
                                                     const float* __restrict__ M,
                                                     const float* __restrict__ yv,
                                                     const float* __restrict__ cb,
                                                     float* __restrict__ ec) {
  __shared__ float ms[64][128];
  __shared__ float red[2][64];
  const int tid = threadIdx.x;
  const int lane = tid & 63;
  const int wave = __builtin_amdgcn_readfirstlane(tid >> 6);
  const int dwave = wave & 1;
  const int ehalf = wave >> 1;
  const int e0 = blockIdx.x * 64;
  const int b = e0 >> EPQ_SHIFT;
  const int d = dwave * 64 + lane;

  float acc[32];
#pragma unroll
  for (int i = 0; i < 32; ++i) acc[i] = 0.f;
  for (int ch = 0; ch < 2; ++ch) {
    __syncthreads();
#pragma unroll
    for (int l = 0; l < 8; ++l) {
      int lin = tid + l * 256;
      int cc = lin >> 5, d4 = (lin & 31) * 4;
      *(float4*)&ms[cc][d4] =
          *(const float4*)&M[(size_t)(128 + ch * 64 + cc) * 512 + 128 + d4];
    }
    __syncthreads();
    for (int c4 = 0; c4 < 16; ++c4) {
      float m0 = ms[c4 * 4 + 0][d];
      float m1 = ms[c4 * 4 + 1][d];
      float m2 = ms[c4 * 4 + 2][d];
      float m3 = ms[c4 * 4 + 3][d];
#pragma unroll
      for (int n = 0; n < 32; ++n) {
        int e = e0 + ehalf * 32 + n;  // wave-uniform -> scalar loads
        float4 r = *(const float4*)&rel[(size_t)e * 128 + ch * 64 + c4 * 4];
        float a = acc[n];
        a += r.x * m0;
        a += r.y * m1;
        a += r.z * m2;
        a += r.w * m3;
        acc[n] = a;
      }
    }
  }
  float yb = yv[b * 128 + d];
#pragma unroll
  for (int n = 0; n < 32; ++n) {
    int e = e0 + ehalf * 32 + n;
    float pe = (acc[n] + yb) * rel[(size_t)e * 128 + d];
#pragma unroll
    for (int m = 32; m >= 1; m >>= 1) pe += __shfl_xor(pe, m, 64);
    if (lane == 0) red[dwave][ehalf * 32 + n] = pe;
  }
  __syncthreads();
  if (tid < 64) ec[e0 + tid] = red[0][tid] + red[1][tid] + cb[b];
}

// ---------------- K5: per-edge logits + segment max ----------------
// 16 lanes per edge, 8 components each.
__global__ __launch_bounds__(256) void k5_logits(const float* __restrict__ rel,
                                                 const float* __restrict__ hv,
                                                 const float* __restrict__ J0,
                                                 const float* __restrict__ J1,
                                                 const float* __restrict__ I1,
                                                 const float* __restrict__ wv,
                                                 const float* __restrict__ uv,
                                                 const float* __restrict__ ec,
                                                 const int* __restrict__ node_i,
                                                 const int* __restrict__ node_j,
                                                 float* __restrict__ logits,
                                                 unsigned* __restrict__ segkey) {
  __shared__ float wl[128];
  __shared__ float ul[128];
  int tid = threadIdx.x;
  int e0 = blockIdx.x * 16;
  int b = e0 >> EPQ_SHIFT;
  if (tid < 128) wl[tid] = wv[b * 128 + tid];
  else ul[tid - 128] = uv[b * 128 + (tid - 128)];
  __syncthreads();
  int lane = tid & 15, eg = tid >> 4;
  int e = e0 + eg;
  int i = node_i[e], j = node_j[e];
  int c0 = lane * 8;

  float rr[8], hi[8], hj[8], a0[8], a1[8], ii[8];
  *(float4*)&rr[0] = *(const float4*)&rel[(size_t)e * 128 + c0];
  *(float4*)&rr[4] = *(const float4*)&rel[(size_t)e * 128 + c0 + 4];
  *(float4*)&hi[0] = *(const float4*)&hv[(size_t)i * 128 + c0];
  *(float4*)&hi[4] = *(const float4*)&hv[(size_t)i * 128 + c0 + 4];
  *(float4*)&hj[0] = *(const float4*)&hv[(size_t)j * 128 + c0];
  *(float4*)&hj[4] = *(const float4*)&hv[(size_t)j * 128 + c0 + 4];
  *(float4*)&a0[0] = *(const float4*)&J0[(size_t)j * 128 + c0];
  *(float4*)&a0[4] = *(const float4*)&J0[(size_t)j * 128 + c0 + 4];
  *(float4*)&a1[0] = *(const float4*)&J1[(size_t)j * 128 + c0];
  *(float4*)&a1[4] = *(const float4*)&J1[(size_t)j * 128 + c0 + 4];
  *(float4*)&ii[0] = *(const float4*)&I1[(size_t)i * 128 + c0];
  *(float4*)&ii[4] = *(const float4*)&I1[(size_t)i * 128 + c0 + 4];

  float p = 0.f;
#pragma unroll
  for (int k = 0; k < 8; ++k) {
    p += hi[k] * a0[k];               // hvi . J0[j]
    p += rr[k] * (a1[k] + ii[k]);     // rel . (J1[j] + I1[i])
    p += hi[k] * wl[c0 + k];          // hvi . w_b
    p += hj[k] * ul[c0 + k];          // hvj . u_b
  }
#pragma unroll
  for (int m = 8; m >= 1; m >>= 1) p += __shfl_xor(p, m, 64);
  if (lane == 0) {
    float lg = p + ec[e];
    logits[e] = lg;
    atomicMax(&segkey[i], enc_f(lg));
  }
}

// ---------------- K6: ex = exp(logit - segmax), segment sum ----------------
__global__ void k6_exp(float* __restrict__ exb, const int* __restrict__ node_i,
                       const unsigned* __restrict__ segkey,
                       float* __restrict__ segsum, int E) {
  int e = blockIdx.x * 256 + threadIdx.x;
  if (e >= E) return;
  int i = node_i[e];
  float m = dec_f(segkey[i]);
  float ex = expf(exb[e] - m);
  exb[e] = ex;
  atomicAdd(&segsum[i], ex);
}

// ---------------- K7: per-query exact top-256 radix select + scatter-add ----
__global__ __launch_bounds__(256) void k7_topk(const float* __restrict__ exb,
                                               const int* __restrict__ node_i,
                                               const int* __restrict__ node_j,
                                               const float* __restrict__ segsum,
                                               const float* __restrict__ score,
                                               float* __restrict__ out) {
  __shared__ unsigned vals[2048];
  __shared__ unsigned hist[256];
  __shared__ unsigned sc[256];
  __shared__ unsigned tie_scan[256];
  __shared__ unsigned sel_info[2];
  int q = blockIdx.x, t = threadIdx.x;
  size_t base = (size_t)q * 2048;
#pragma unroll
  for (int l = 0; l < 8; ++l) {
    int el = t * 8 + l;
    int i = node_i[base + el];
    float tgt = exb[base + el] / segsum[i] * score[i];  // attn * src_score >= 0
    vals[el] = __float_as_uint(tgt);
  }
  __syncthreads();
  unsigned prefix = 0, need = KSEL;
  for (int pass = 3; pass >= 0; --pass) {
    hist[t] = 0;
    __syncthreads();
    int sh = pass * 8;
#pragma unroll
    for (int l = 0; l < 8; ++l) {
      unsigned v = vals[t * 8 + l];
      bool match = (pass == 3) || ((v >> (sh + 8)) == (prefix >> (sh + 8)));
      if (match) atomicAdd(&hist[(v >> sh) & 255u], 1u);
    }
    __syncthreads();
    sc[t] = hist[t];
    __syncthreads();
    for (int off = 1; off < 256; off <<= 1) {  // suffix-inclusive sum
      unsigned add = (t + off < 256) ? sc[t + off] : 0u;
      __syncthreads();
      sc[t] += add;
      __syncthreads();
    }
    unsigned above = sc[t] - hist[t];
    if (above < need && need <= sc[t]) {
      sel_info[0] = (unsigned)t;
      sel_info[1] = need - above;
    }
    __syncthreads();
    prefix |= sel_info[0] << sh;
    need = sel_info[1];
    __syncthreads();
  }
  unsigned T = prefix, r = need;
  unsigned lc = 0;
#pragma unroll
  for (int l = 0; l < 8; ++l)
    if (vals[t * 8 + l] == T) lc++;
  tie_scan[t] = lc;
  __syncthreads();
  unsigned own = lc;
  for (int off = 1; off < 256; off <<= 1) {
    unsigned add = (t >= off) ? tie_scan[t - off] : 0u;
    __syncthreads();
    tie_scan[t] += add;
    __syncthreads();
  }
  unsigned excl = tie_scan[t] - own;
  unsigned cnt = 0;
#pragma unroll
  for (int l = 0; l < 8; ++l) {
    int el = t * 8 + l;
    unsigned v = vals[el];
    bool take = false;
    if (v > T) take = true;
    else if (v == T) { if (excl + cnt < r) take = true; cnt++; }
    if (take) {
      int j = node_j[base + el];
      atomicAdd(&out[j], __uint_as_float(v));
    }
  }
}

// ---------------- host ----------------
extern "C" void kernel_launch(void* const* d_in, const int* in_sizes, int n_in,
                              void* d_out, int out_size, void* d_ws, size_t ws_size,
                              hipStream_t stream) {
  const float* score = (const float*)d_in[0];
  const float* hv    = (const float*)d_in[1];
  const float* rel   = (const float*)d_in[2];
  const float* qsrc  = (const float*)d_in[3];
  const float* qrel  = (const float*)d_in[4];
  const float* Wq    = (const float*)d_in[5];
  const float* Wk    = (const float*)d_in[6];
  const int* node_i  = (const int*)d_in[8];
  const int* node_j  = (const int*)d_in[9];

  const int N = in_sizes[0];            // 50000
  const int B = in_sizes[3] / 128;      // 64
  const int E = in_sizes[2] / 128;      // 131072

  float* ws = (float*)d_ws;
  float* M  = ws;
  float* Mt = M + 262144;
  float* J0 = Mt + 262144;
  float* J1 = J0 + (size_t)N * 128;
  float* I1 = J1 + (size_t)N * 128;
  float* wv = I1 + (size_t)N * 128;
  float* uv = wv + (size_t)B * 128;
  float* yv = uv + (size_t)B * 128;
  float* cb = yv + (size_t)B * 128;
  float* ec = cb + B;
  float* exb = ec + E;
  unsigned* segkey = (unsigned*)(exb + E);
  float* segsum = (float*)(segkey + N);
  float* out = (float*)d_out;

  k0_init<<<(N + 255) / 256, 256, 0, stream>>>(out, segsum, segkey, N);
  k1_gemmM<<<dim3(8, 8), 256, 0, stream>>>(Wq, Wk, M, Mt);
  k2m_proj<<<(N + 63) / 64, 256, 0, stream>>>(hv, M, Mt, J0, J1, I1, N);
  k3_query<<<B, 128, 0, stream>>>(qsrc, qrel, M, Mt, wv, uv, yv, cb);
  k4m_edgeconst<<<E / 64, 256, 0, stream>>>(rel, M, yv, cb, ec);
  k5_logits<<<E / 16, 256, 0, stream>>>(rel, hv, J0, J1, I1, wv, uv, ec,
                                        node_i, node_j, exb, segkey);
  k6_exp<<<(E + 255) / 256, 256, 0, stream>>>(exb, node_i, segkey, segsum, E);
  k7_topk<<<B, 256, 0, stream>>>(exb, node_i, node_j, segsum, score, out);
}

// Round 3
// 342.231 us; speedup vs baseline: 1.8320x; 1.8320x over previous
//
#include <hip/hip_runtime.h>
#include <cstddef>

// Problem constants (fixed by the reference)
#define EPQ_SHIFT 11       // EPQ = 2048
#define KSEL 256

__device__ __forceinline__ unsigned enc_f(float f) {
  unsigned u = __float_as_uint(f);
  return (u & 0x80000000u) ? ~u : (u | 0x80000000u);
}
__device__ __forceinline__ float dec_f(unsigned k) {
  unsigned u = (k & 0x80000000u) ? (k ^ 0x80000000u) : ~k;
  return __uint_as_float(u);
}

// ---------------- K0: init output + segment buffers ----------------
__global__ void k0_init(float* __restrict__ out, float* __restrict__ segsum,
                        unsigned* __restrict__ segkey, int n) {
  int i = blockIdx.x * 256 + threadIdx.x;
  if (i < n) { out[i] = 0.f; segsum[i] = 0.f; segkey[i] = 0u; }
}

// ---------------- K1: M = Wq^T Wk (512x512), also Mt = M^T ----------------
__global__ __launch_bounds__(256) void k1_gemmM(const float* __restrict__ Wq,
                                                const float* __restrict__ Wk,
                                                float* __restrict__ M,
                                                float* __restrict__ Mt) {
  __shared__ float as[16][64];
  __shared__ float bs[16][64];
  int tid = threadIdx.x;
  int tx = tid & 15, ty = tid >> 4;
  int c1b = blockIdx.y * 64, c2b = blockIdx.x * 64;
  float acc[4][4] = {};
  for (int k0 = 0; k0 < 512; k0 += 16) {
#pragma unroll
    for (int l = 0; l < 4; ++l) {
      int lin = tid + l * 256;
      int kk = lin >> 6, c = lin & 63;
      as[kk][c] = Wq[(k0 + kk) * 512 + c1b + c];
      bs[kk][c] = Wk[(k0 + kk) * 512 + c2b + c];
    }
    __syncthreads();
#pragma unroll
    for (int kk = 0; kk < 16; ++kk) {
      float a[4], b[4];
#pragma unroll
      for (int m = 0; m < 4; ++m) a[m] = as[kk][ty * 4 + m];
#pragma unroll
      for (int n = 0; n < 4; ++n) b[n] = bs[kk][tx * 4 + n];
#pragma unroll
      for (int m = 0; m < 4; ++m)
#pragma unroll
        for (int n = 0; n < 4; ++n) acc[m][n] += a[m] * b[n];
    }
    __syncthreads();
  }
#pragma unroll
  for (int m = 0; m < 4; ++m)
#pragma unroll
    for (int n = 0; n < 4; ++n) {
      int c1 = c1b + ty * 4 + m, c2 = c2b + tx * 4 + n;
      M[c1 * 512 + c2] = acc[m][n];
      Mt[c2 * 512 + c1] = acc[m][n];
    }
}

// ---------------- K2v3: node projections, 128n x 128d block, 8x8 reg tile ----
// blockIdx.x = p (projection), blockIdx.y = node tile.
// hsT[c][n] in LDS (stride 132: conflict-free b128 reads, b128-aligned rows);
// M coefficients streamed from global (L2-resident, 256B/wave coalesced).
// p=0: J0[n][d] = sum_c M[d][c]     hv[n][c]  -> coeff = Mt[c*512 + d]
// p=1: J1[n][d] = sum_c M[128+d][c] hv[n][c]  -> coeff = Mt[c*512 + 128 + d]
// p=2: I1[n][d] = sum_c M[c][128+d] hv[n][c]  -> coeff = M [c*512 + 128 + d]
__global__ __launch_bounds__(256) void k2v3_proj(const float* __restrict__ hv,
                                                 const float* __restrict__ M,
                                                 const float* __restrict__ Mt,
                                                 float* __restrict__ J0,
                                                 float* __restrict__ J1,
                                                 float* __restrict__ I1, int N) {
  __shared__ float hsT[64][132];
  const int tid = threadIdx.x;
  const int tx = tid & 15, ty = tid >> 4;
  const int p = blockIdx.x;
  const int n0 = blockIdx.y * 128;
  const float* base = (p == 0) ? Mt : (p == 1) ? (Mt + 128) : (M + 128);
  float* outp = (p == 0) ? J0 : (p == 1) ? J1 : I1;

  float acc[8][8] = {};  // [n-sub: ty*4+0..3, 64+ty*4+0..3][d-sub: tx*4.., 64+tx*4..]
  for (int ch = 0; ch < 2; ++ch) {
    __syncthreads();
    {  // stage hsT[c][n] = hv[n0+n][ch*64+c]  (transpose in LDS)
      int c4 = (tid & 15) * 4;
      int g = tid >> 4;
#pragma unroll
      for (int l = 0; l < 8; ++l) {
        int n = l * 16 + g;
        int gn = n0 + n;
        gn = gn < N ? gn : N - 1;
        float4 h = *(const float4*)&hv[(size_t)gn * 128 + ch * 64 + c4];
        hsT[c4 + 0][n] = h.x;
        hsT[c4 + 1][n] = h.y;
        hsT[c4 + 2][n] = h.z;
        hsT[c4 + 3][n] = h.w;
      }
    }
    __syncthreads();
    const float* mrow = base + (size_t)(ch * 64) * 512;
#pragma unroll 2
    for (int c = 0; c < 64; ++c) {
      float4 h0 = *(const float4*)&hsT[c][ty * 4];
      float4 h1 = *(const float4*)&hsT[c][64 + ty * 4];
      float4 m0 = *(const float4*)&mrow[(size_t)c * 512 + tx * 4];
      float4 m1 = *(const float4*)&mrow[(size_t)c * 512 + 64 + tx * 4];
      float hn[8] = {h0.x, h0.y, h0.z, h0.w, h1.x, h1.y, h1.z, h1.w};
      float md[8] = {m0.x, m0.y, m0.z, m0.w, m1.x, m1.y, m1.z, m1.w};
#pragma unroll
      for (int n = 0; n < 8; ++n)
#pragma unroll
        for (int d = 0; d < 8; ++d) acc[n][d] += hn[n] * md[d];
    }
  }
#pragma unroll
  for (int nn = 0; nn < 8; ++nn) {
    int nl = (nn < 4) ? (ty * 4 + nn) : (64 + ty * 4 + nn - 4);
    int gn = n0 + nl;
    if (gn < N) {
      float4 o0 = {acc[nn][0], acc[nn][1], acc[nn][2], acc[nn][3]};
      float4 o1 = {acc[nn][4], acc[nn][5], acc[nn][6], acc[nn][7]};
      *(float4*)&outp[(size_t)gn * 128 + tx * 4] = o0;
      *(float4*)&outp[(size_t)gn * 128 + 64 + tx * 4] = o1;
    }
  }
}

// ---------------- K3: per-query vectors w,u,y and scalar c_b ----------------
__global__ __launch_bounds__(128) void k3_query(const float* __restrict__ qsrc,
                                                const float* __restrict__ qrel,
                                                const float* __restrict__ M,
                                                const float* __restrict__ Mt,
                                                float* __restrict__ wv,
                                                float* __restrict__ uv,
                                                float* __restrict__ yv,
                                                float* __restrict__ cb) {
  __shared__ float qcat[256];
  __shared__ float red[128];
  int b = blockIdx.x, d = threadIdx.x;
  qcat[d] = qsrc[b * 128 + d];
  qcat[128 + d] = qrel[b * 128 + d];
  __syncthreads();
  float w = 0.f, u = 0.f, y = 0.f, t1 = 0.f, t2 = 0.f;
  for (int c = 0; c < 256; ++c) {
    float q = qcat[c];
    size_t row = (size_t)(256 + c) * 512;
    w += Mt[row + d] * q;                        // M[d][256+c]
    u += M[row + d] * q;                         // M[256+c][d]
    y += (Mt[row + 128 + d] + M[row + 128 + d]) * q;  // x + v
    t1 += M[row + 256 + d] * q;                  // for c_b, col 256+d
    t2 += M[row + 384 + d] * q;                  // for c_b, col 384+d
  }
  wv[b * 128 + d] = w;
  uv[b * 128 + d] = u;
  yv[b * 128 + d] = y;
  red[d] = qcat[d] * t1 + qcat[128 + d] * t2;
  __syncthreads();
  for (int s = 64; s > 0; s >>= 1) {
    if (d < s) red[d] += red[d + s];
    __syncthreads();
  }
  if (d == 0) cb[b] = red[0];
}

// ---------------- K4v3: edge_const, 64e x 128c block, 4x8 reg tile ----------
// GEMM2: acc[e][c] = sum_d M11[c][d] * rel[e][d]  (coeff = Mt[(128+d)*512+128+c],
// contiguous in c), then ec[e] = sum_c (acc[e][c] + y_b[c]) * rel[e][c] + c_b.
__global__ __launch_bounds__(256) void k4v3_edgeconst(const float* __restrict__ rel,
                                                      const float* __restrict__ Mt,
                                                      const float* __restrict__ yv,
                                                      const float* __restrict__ cb,
                                                      float* __restrict__ ec) {
  __shared__ float rT[128][68];   // rT[c][e] = rel[e0+e][c]
  __shared__ float red[64][17];
  const int tid = threadIdx.x;
  const int tx = tid & 15, ty = tid >> 4;
  const int e0 = blockIdx.x * 64;
  const int b = e0 >> EPQ_SHIFT;

  {  // stage transpose
    int c4 = (tid & 31) * 4;
    int g = tid >> 5;
#pragma unroll
    for (int l = 0; l < 8; ++l) {
      int e = l * 8 + g;
      float4 r = *(const float4*)&rel[(size_t)(e0 + e) * 128 + c4];
      rT[c4 + 0][e] = r.x;
      rT[c4 + 1][e] = r.y;
      rT[c4 + 2][e] = r.z;
      rT[c4 + 3][e] = r.w;
    }
  }
  __syncthreads();

  float acc[4][8] = {};  // [e-sub: ty*4+0..3][c-sub: tx*4.., 64+tx*4..]
  const float* mbase = Mt + (size_t)128 * 512 + 128;
#pragma unroll 2
  for (int d = 0; d < 128; ++d) {
    float4 r0 = *(const float4*)&rT[d][ty * 4];
    float4 m0 = *(const float4*)&mbase[(size_t)d * 512 + tx * 4];
    float4 m1 = *(const float4*)&mbase[(size_t)d * 512 + 64 + tx * 4];
    float re[4] = {r0.x, r0.y, r0.z, r0.w};
    float mc[8] = {m0.x, m0.y, m0.z, m0.w, m1.x, m1.y, m1.z, m1.w};
#pragma unroll
    for (int e = 0; e < 4; ++e)
#pragma unroll
      for (int c = 0; c < 8; ++c) acc[e][c] += re[e] * mc[c];
  }

  // contraction with rel + y_b
  float4 yb0 = *(const float4*)&yv[b * 128 + tx * 4];
  float4 yb1 = *(const float4*)&yv[b * 128 + 64 + tx * 4];
  float yb[8] = {yb0.x, yb0.y, yb0.z, yb0.w, yb1.x, yb1.y, yb1.z, yb1.w};
  float part[4] = {};
#pragma unroll
  for (int cc = 0; cc < 8; ++cc) {
    int c = (cc < 4) ? (tx * 4 + cc) : (64 + tx * 4 + cc - 4);
    float4 rr = *(const float4*)&rT[c][ty * 4];
    float rv[4] = {rr.x, rr.y, rr.z, rr.w};
#pragma unroll
    for (int e = 0; e < 4; ++e) part[e] += (acc[e][cc] + yb[cc]) * rv[e];
  }
#pragma unroll
  for (int e = 0; e < 4; ++e) red[ty * 4 + e][tx] = part[e];
  __syncthreads();
  if (tid < 64) {
    float s = 0.f;
#pragma unroll
    for (int k = 0; k < 16; ++k) s += red[tid][k];
    ec[e0 + tid] = s + cb[b];
  }
}

// ---------------- K5: per-edge logits + segment max ----------------
__global__ __launch_bounds__(256) void k5_logits(const float* __restrict__ rel,
                                                 const float* __restrict__ hv,
                                                 const float* __restrict__ J0,
                                                 const float* __restrict__ J1,
                                                 const float* __restrict__ I1,
                                                 const float* __restrict__ wv,
                                                 const float* __restrict__ uv,
                                                 const float* __restrict__ ec,
                                                 const int* __restrict__ node_i,
                                                 const int* __restrict__ node_j,
                                                 float* __restrict__ logits,
                                                 unsigned* __restrict__ segkey) {
  __shared__ float wl[128];
  __shared__ float ul[128];
  int tid = threadIdx.x;
  int e0 = blockIdx.x * 16;
  int b = e0 >> EPQ_SHIFT;
  if (tid < 128) wl[tid] = wv[b * 128 + tid];
  else ul[tid - 128] = uv[b * 128 + (tid - 128)];
  __syncthreads();
  int lane = tid & 15, eg = tid >> 4;
  int e = e0 + eg;
  int i = node_i[e], j = node_j[e];
  int c0 = lane * 8;

  float rr[8], hi[8], hj[8], a0[8], a1[8], ii[8];
  *(float4*)&rr[0] = *(const float4*)&rel[(size_t)e * 128 + c0];
  *(float4*)&rr[4] = *(const float4*)&rel[(size_t)e * 128 + c0 + 4];
  *(float4*)&hi[0] = *(const float4*)&hv[(size_t)i * 128 + c0];
  *(float4*)&hi[4] = *(const float4*)&hv[(size_t)i * 128 + c0 + 4];
  *(float4*)&hj[0] = *(const float4*)&hv[(size_t)j * 128 + c0];
  *(float4*)&hj[4] = *(const float4*)&hv[(size_t)j * 128 + c0 + 4];
  *(float4*)&a0[0] = *(const float4*)&J0[(size_t)j * 128 + c0];
  *(float4*)&a0[4] = *(const float4*)&J0[(size_t)j * 128 + c0 + 4];
  *(float4*)&a1[0] = *(const float4*)&J1[(size_t)j * 128 + c0];
  *(float4*)&a1[4] = *(const float4*)&J1[(size_t)j * 128 + c0 + 4];
  *(float4*)&ii[0] = *(const float4*)&I1[(size_t)i * 128 + c0];
  *(float4*)&ii[4] = *(const float4*)&I1[(size_t)i * 128 + c0 + 4];

  float p = 0.f;
#pragma unroll
  for (int k = 0; k < 8; ++k) {
    p += hi[k] * a0[k];               // hvi . J0[j]
    p += rr[k] * (a1[k] + ii[k]);     // rel . (J1[j] + I1[i])
    p += hi[k] * wl[c0 + k];          // hvi . w_b
    p += hj[k] * ul[c0 + k];          // hvj . u_b
  }
#pragma unroll
  for (int m = 8; m >= 1; m >>= 1) p += __shfl_xor(p, m, 64);
  if (lane == 0) {
    float lg = p + ec[e];
    logits[e] = lg;
    atomicMax(&segkey[i], enc_f(lg));
  }
}

// ---------------- K6: ex = exp(logit - segmax), segment sum ----------------
__global__ void k6_exp(float* __restrict__ exb, const int* __restrict__ node_i,
                       const unsigned* __restrict__ segkey,
                       float* __restrict__ segsum, int E) {
  int e = blockIdx.x * 256 + threadIdx.x;
  if (e >= E) return;
  int i = node_i[e];
  float m = dec_f(segkey[i]);
  float ex = expf(exb[e] - m);
  exb[e] = ex;
  atomicAdd(&segsum[i], ex);
}

// ---------------- K7: per-query exact top-256 radix select + scatter-add ----
__global__ __launch_bounds__(256) void k7_topk(const float* __restrict__ exb,
                                               const int* __restrict__ node_i,
                                               const int* __restrict__ node_j,
                                               const float* __restrict__ segsum,
                                               const float* __restrict__ score,
                                               float* __restrict__ out) {
  __shared__ unsigned vals[2048];
  __shared__ unsigned hist[256];
  __shared__ unsigned sc[256];
  __shared__ unsigned tie_scan[256];
  __shared__ unsigned sel_info[2];
  int q = blockIdx.x, t = threadIdx.x;
  size_t base = (size_t)q * 2048;
#pragma unroll
  for (int l = 0; l < 8; ++l) {
    int el = t * 8 + l;
    int i = node_i[base + el];
    float tgt = exb[base + el] / segsum[i] * score[i];  // attn * src_score >= 0
    vals[el] = __float_as_uint(tgt);
  }
  __syncthreads();
  unsigned prefix = 0, need = KSEL;
  for (int pass = 3; pass >= 0; --pass) {
    hist[t] = 0;
    __syncthreads();
    int sh = pass * 8;
#pragma unroll
    for (int l = 0; l < 8; ++l) {
      unsigned v = vals[t * 8 + l];
      bool match = (pass == 3) || ((v >> (sh + 8)) == (prefix >> (sh + 8)));
      if (match) atomicAdd(&hist[(v >> sh) & 255u], 1u);
    }
    __syncthreads();
    sc[t] = hist[t];
    __syncthreads();
    for (int off = 1; off < 256; off <<= 1) {  // suffix-inclusive sum
      unsigned add = (t + off < 256) ? sc[t + off] : 0u;
      __syncthreads();
      sc[t] += add;
      __syncthreads();
    }
    unsigned above = sc[t] - hist[t];
    if (above < need && need <= sc[t]) {
      sel_info[0] = (unsigned)t;
      sel_info[1] = need - above;
    }
    __syncthreads();
    prefix |= sel_info[0] << sh;
    need = sel_info[1];
    __syncthreads();
  }
  unsigned T = prefix, r = need;
  unsigned lc = 0;
#pragma unroll
  for (int l = 0; l < 8; ++l)
    if (vals[t * 8 + l] == T) lc++;
  tie_scan[t] = lc;
  __syncthreads();
  unsigned own = lc;
  for (int off = 1; off < 256; off <<= 1) {
    unsigned add = (t >= off) ? tie_scan[t - off] : 0u;
    __syncthreads();
    tie_scan[t] += add;
    __syncthreads();
  }
  unsigned excl = tie_scan[t] - own;
  unsigned cnt = 0;
#pragma unroll
  for (int l = 0; l < 8; ++l) {
    int el = t * 8 + l;
    unsigned v = vals[el];
    bool take = false;
    if (v > T) take = true;
    else if (v == T) { if (excl + cnt < r) take = true; cnt++; }
    if (take) {
      int j = node_j[base + el];
      atomicAdd(&out[j], __uint_as_float(v));
    }
  }
}

// ---------------- host ----------------
extern "C" void kernel_launch(void* const* d_in, const int* in_sizes, int n_in,
                              void* d_out, int out_size, void* d_ws, size_t ws_size,
                              hipStream_t stream) {
  const float* score = (const float*)d_in[0];
  const float* hv    = (const float*)d_in[1];
  const float* rel   = (const float*)d_in[2];
  const float* qsrc  = (const float*)d_in[3];
  const float* qrel  = (const float*)d_in[4];
  const float* Wq    = (const float*)d_in[5];
  const float* Wk    = (const float*)d_in[6];
  const int* node_i  = (const int*)d_in[8];
  const int* node_j  = (const int*)d_in[9];

  const int N = in_sizes[0];            // 50000
  const int B = in_sizes[3] / 128;      // 64
  const int E = in_sizes[2] / 128;      // 131072

  float* ws = (float*)d_ws;
  float* M  = ws;
  float* Mt = M + 262144;
  float* J0 = Mt + 262144;
  float* J1 = J0 + (size_t)N * 128;
  float* I1 = J1 + (size_t)N * 128;
  float* wv = I1 + (size_t)N * 128;
  float* uv = wv + (size_t)B * 128;
  float* yv = uv + (size_t)B * 128;
  float* cb = yv + (size_t)B * 128;
  float* ec = cb + B;
  float* exb = ec + E;
  unsigned* segkey = (unsigned*)(exb + E);
  float* segsum = (float*)(segkey + N);
  float* out = (float*)d_out;

  k0_init<<<(N + 255) / 256, 256, 0, stream>>>(out, segsum, segkey, N);
  k1_gemmM<<<dim3(8, 8), 256, 0, stream>>>(Wq, Wk, M, Mt);
  k2v3_proj<<<dim3(3, (N + 127) / 128), 256, 0, stream>>>(hv, M, Mt, J0, J1, I1, N);
  k3_query<<<B, 128, 0, stream>>>(qsrc, qrel, M, Mt, wv, uv, yv, cb);
  k4v3_edgeconst<<<E / 64, 256, 0, stream>>>(rel, Mt, yv, cb, ec);
  k5_logits<<<E / 16, 256, 0, stream>>>(rel, hv, J0, J1, I1, wv, uv, ec,
                                        node_i, node_j, exb, segkey);
  k6_exp<<<(E + 255) / 256, 256, 0, stream>>>(exb, node_i, segkey, segsum, E);
  k7_topk<<<B, 256, 0, stream>>>(exb, node_i, node_j, segsum, score, out);
}

// Round 4
// 265.703 us; speedup vs baseline: 2.3597x; 1.2880x over previous
//
#include <hip/hip_runtime.h>
#include <cstddef>

// Problem constants (fixed by the reference)
#define EPQ_SHIFT 11       // EPQ = 2048
#define KSEL 256

__device__ __forceinline__ unsigned enc_f(float f) {
  unsigned u = __float_as_uint(f);
  return (u & 0x80000000u) ? ~u : (u | 0x80000000u);
}
__device__ __forceinline__ float dec_f(unsigned k) {
  unsigned u = (k & 0x80000000u) ? (k ^ 0x80000000u) : ~k;
  return __uint_as_float(u);
}

// ---------------- K0: init output + segment buffers ----------------
__global__ void k0_init(float* __restrict__ out, float* __restrict__ segsum,
                        unsigned* __restrict__ segkey, int n) {
  int i = blockIdx.x * 256 + threadIdx.x;
  if (i < n) { out[i] = 0.f; segsum[i] = 0.f; segkey[i] = 0u; }
}

// ---------------- K1: M = Wq^T Wk (512x512), also Mt = M^T ----------------
__global__ __launch_bounds__(256) void k1_gemmM(const float* __restrict__ Wq,
                                                const float* __restrict__ Wk,
                                                float* __restrict__ M,
                                                float* __restrict__ Mt) {
  __shared__ float as[16][64];
  __shared__ float bs[16][64];
  int tid = threadIdx.x;
  int tx = tid & 15, ty = tid >> 4;
  int c1b = blockIdx.y * 64, c2b = blockIdx.x * 64;
  float acc[4][4] = {};
  for (int k0 = 0; k0 < 512; k0 += 16) {
#pragma unroll
    for (int l = 0; l < 4; ++l) {
      int lin = tid + l * 256;
      int kk = lin >> 6, c = lin & 63;
      as[kk][c] = Wq[(k0 + kk) * 512 + c1b + c];
      bs[kk][c] = Wk[(k0 + kk) * 512 + c2b + c];
    }
    __syncthreads();
#pragma unroll
    for (int kk = 0; kk < 16; ++kk) {
      float a[4], b[4];
#pragma unroll
      for (int m = 0; m < 4; ++m) a[m] = as[kk][ty * 4 + m];
#pragma unroll
      for (int n = 0; n < 4; ++n) b[n] = bs[kk][tx * 4 + n];
#pragma unroll
      for (int m = 0; m < 4; ++m)
#pragma unroll
        for (int n = 0; n < 4; ++n) acc[m][n] += a[m] * b[n];
    }
    __syncthreads();
  }
#pragma unroll
  for (int m = 0; m < 4; ++m)
#pragma unroll
    for (int n = 0; n < 4; ++n) {
      int c1 = c1b + ty * 4 + m, c2 = c2b + tx * 4 + n;
      M[c1 * 512 + c2] = acc[m][n];
      Mt[c2 * 512 + c1] = acc[m][n];
    }
}

// ===== shared GEMM micro-kernel layout =====
// 256 threads (tx=tid&15, ty=tid>>4); output tile 128 rows x 128 cols;
// rows: ty*4+{0..3} and 64+ty*4+{0..3}; cols: tx*4+{0..3} and 64+tx*4+{0..3}.
// Contraction over 128 in 2 chunks of 64.
// hsT[c][row'] : transposed LDS tile of the row-operand, XOR-swizzled columns
//   (write: col^((tx&7)<<2) with c-rows tx*4+k; read: col^(((c>>2)&7)<<2)).
// ms[c][col]   : coefficient tile, linear (reads are 2-way/broadcast = free).

// ---------------- K2v4: node projections J0/J1/I1 ----------------
// p=0: J0[n][d] = sum_c M[d][c]     hv[n][c]  -> coeff = Mt[c*512 + d]
// p=1: J1[n][d] = sum_c M[128+d][c] hv[n][c]  -> coeff = Mt[c*512 + 128 + d]
// p=2: I1[n][d] = sum_c M[c][128+d] hv[n][c]  -> coeff = M [c*512 + 128 + d]
__global__ __launch_bounds__(256) void k2v4_proj(const float* __restrict__ hv,
                                                 const float* __restrict__ M,
                                                 const float* __restrict__ Mt,
                                                 float* __restrict__ J0,
                                                 float* __restrict__ J1,
                                                 float* __restrict__ I1, int N) {
  __shared__ float hsT[64][132];
  __shared__ float ms[64][132];
  const int tid = threadIdx.x;
  const int tx = tid & 15, ty = tid >> 4;
  const int p = blockIdx.x;
  const int n0 = blockIdx.y * 128;
  const float* base = (p == 0) ? Mt : (p == 1) ? (Mt + 128) : (M + 128);
  float* outp = (p == 0) ? J0 : (p == 1) ? J1 : I1;

  float acc[8][8] = {};
  for (int ch = 0; ch < 2; ++ch) {
    __syncthreads();
    {  // stage hv transposed, swizzled
      const int swz = (tx & 7) << 2;
#pragma unroll
      for (int l = 0; l < 8; ++l) {
        int n = l * 16 + ty;
        int gn = n0 + n;
        gn = gn < N ? gn : N - 1;
        float4 h = *(const float4*)&hv[(size_t)gn * 128 + ch * 64 + tx * 4];
        int col = n ^ swz;
        hsT[tx * 4 + 0][col] = h.x;
        hsT[tx * 4 + 1][col] = h.y;
        hsT[tx * 4 + 2][col] = h.z;
        hsT[tx * 4 + 3][col] = h.w;
      }
    }
    {  // stage coefficient tile (linear)
#pragma unroll
      for (int l = 0; l < 8; ++l) {
        int lin = tid + l * 256;
        int cc = lin >> 5, d4 = (lin & 31) * 4;
        *(float4*)&ms[cc][d4] =
            *(const float4*)&base[(size_t)(ch * 64 + cc) * 512 + d4];
      }
    }
    __syncthreads();
#pragma unroll 2
    for (int c = 0; c < 64; ++c) {
      int hcol = (ty * 4) ^ (((c >> 2) & 7) << 2);
      float4 h0 = *(const float4*)&hsT[c][hcol];
      float4 h1 = *(const float4*)&hsT[c][64 + hcol];
      float4 m0 = *(const float4*)&ms[c][tx * 4];
      float4 m1 = *(const float4*)&ms[c][64 + tx * 4];
      float hn[8] = {h0.x, h0.y, h0.z, h0.w, h1.x, h1.y, h1.z, h1.w};
      float md[8] = {m0.x, m0.y, m0.z, m0.w, m1.x, m1.y, m1.z, m1.w};
#pragma unroll
      for (int n = 0; n < 8; ++n)
#pragma unroll
        for (int d = 0; d < 8; ++d) acc[n][d] += hn[n] * md[d];
    }
  }
#pragma unroll
  for (int nn = 0; nn < 8; ++nn) {
    int nl = (nn < 4) ? (ty * 4 + nn) : (64 + ty * 4 + nn - 4);
    int gn = n0 + nl;
    if (gn < N) {
      float4 o0 = {acc[nn][0], acc[nn][1], acc[nn][2], acc[nn][3]};
      float4 o1 = {acc[nn][4], acc[nn][5], acc[nn][6], acc[nn][7]};
      *(float4*)&outp[(size_t)gn * 128 + tx * 4] = o0;
      *(float4*)&outp[(size_t)gn * 128 + 64 + tx * 4] = o1;
    }
  }
}

// ---------------- K3: per-query vectors w,u,y and scalar c_b ----------------
__global__ __launch_bounds__(128) void k3_query(const float* __restrict__ qsrc,
                                                const float* __restrict__ qrel,
                                                const float* __restrict__ M,
                                                const float* __restrict__ Mt,
                                                float* __restrict__ wv,
                                                float* __restrict__ uv,
                                                float* __restrict__ yv,
                                                float* __restrict__ cb) {
  __shared__ float qcat[256];
  __shared__ float red[128];
  int b = blockIdx.x, d = threadIdx.x;
  qcat[d] = qsrc[b * 128 + d];
  qcat[128 + d] = qrel[b * 128 + d];
  __syncthreads();
  float w = 0.f, u = 0.f, y = 0.f, t1 = 0.f, t2 = 0.f;
  for (int c = 0; c < 256; ++c) {
    float q = qcat[c];
    size_t row = (size_t)(256 + c) * 512;
    w += Mt[row + d] * q;                        // M[d][256+c]
    u += M[row + d] * q;                         // M[256+c][d]
    y += (Mt[row + 128 + d] + M[row + 128 + d]) * q;  // x + v
    t1 += M[row + 256 + d] * q;                  // for c_b, col 256+d
    t2 += M[row + 384 + d] * q;                  // for c_b, col 384+d
  }
  wv[b * 128 + d] = w;
  uv[b * 128 + d] = u;
  yv[b * 128 + d] = y;
  red[d] = qcat[d] * t1 + qcat[128 + d] * t2;
  __syncthreads();
  for (int s = 64; s > 0; s >>= 1) {
    if (d < s) red[d] += red[d + s];
    __syncthreads();
  }
  if (d == 0) cb[b] = red[0];
}

// ---------------- K4v4: edge_const via same micro-kernel ----------------
// GEMM: q[e][d] = sum_c rel[e][c] * M11[c][d], coeff = M[(128+c)*512+128+d];
// epilogue: ec[e] = sum_d (q[e][d] + y_b[d]) * rel[e][d] + c_b
// (rel tile reloaded from global/L2 for the dot; shuffle-reduce over tx).
__global__ __launch_bounds__(256) void k4v4_edgeconst(const float* __restrict__ rel,
                                                      const float* __restrict__ M,
                                                      const float* __restrict__ yv,
                                                      const float* __restrict__ cb,
                                                      float* __restrict__ ec) {
  __shared__ float hsT[64][132];
  __shared__ float ms[64][132];
  const int tid = threadIdx.x;
  const int tx = tid & 15, ty = tid >> 4;
  const int e0 = blockIdx.x * 128;
  const int b = e0 >> EPQ_SHIFT;
  const float* base = M + (size_t)128 * 512 + 128;

  float acc[8][8] = {};
  for (int ch = 0; ch < 2; ++ch) {
    __syncthreads();
    {
      const int swz = (tx & 7) << 2;
#pragma unroll
      for (int l = 0; l < 8; ++l) {
        int n = l * 16 + ty;
        float4 h = *(const float4*)&rel[(size_t)(e0 + n) * 128 + ch * 64 + tx * 4];
        int col = n ^ swz;
        hsT[tx * 4 + 0][col] = h.x;
        hsT[tx * 4 + 1][col] = h.y;
        hsT[tx * 4 + 2][col] = h.z;
        hsT[tx * 4 + 3][col] = h.w;
      }
    }
    {
#pragma unroll
      for (int l = 0; l < 8; ++l) {
        int lin = tid + l * 256;
        int cc = lin >> 5, d4 = (lin & 31) * 4;
        *(float4*)&ms[cc][d4] =
            *(const float4*)&base[(size_t)(ch * 64 + cc) * 512 + d4];
      }
    }
    __syncthreads();
#pragma unroll 2
    for (int c = 0; c < 64; ++c) {
      int hcol = (ty * 4) ^ (((c >> 2) & 7) << 2);
      float4 h0 = *(const float4*)&hsT[c][hcol];
      float4 h1 = *(const float4*)&hsT[c][64 + hcol];
      float4 m0 = *(const float4*)&ms[c][tx * 4];
      float4 m1 = *(const float4*)&ms[c][64 + tx * 4];
      float hn[8] = {h0.x, h0.y, h0.z, h0.w, h1.x, h1.y, h1.z, h1.w};
      float md[8] = {m0.x, m0.y, m0.z, m0.w, m1.x, m1.y, m1.z, m1.w};
#pragma unroll
      for (int n = 0; n < 8; ++n)
#pragma unroll
        for (int d = 0; d < 8; ++d) acc[n][d] += hn[n] * md[d];
    }
  }

  // epilogue: dot with rel + y_b, reduce across tx (16 consecutive lanes)
  float4 yb0 = *(const float4*)&yv[b * 128 + tx * 4];
  float4 yb1 = *(const float4*)&yv[b * 128 + 64 + tx * 4];
  float yb[8] = {yb0.x, yb0.y, yb0.z, yb0.w, yb1.x, yb1.y, yb1.z, yb1.w};
  float cbb = cb[b];
#pragma unroll
  for (int nn = 0; nn < 8; ++nn) {
    int nl = (nn < 4) ? (ty * 4 + nn) : (64 + ty * 4 + nn - 4);
    int e = e0 + nl;
    float4 r0 = *(const float4*)&rel[(size_t)e * 128 + tx * 4];
    float4 r1 = *(const float4*)&rel[(size_t)e * 128 + 64 + tx * 4];
    float rv[8] = {r0.x, r0.y, r0.z, r0.w, r1.x, r1.y, r1.z, r1.w};
    float p = 0.f;
#pragma unroll
    for (int d = 0; d < 8; ++d) p += (acc[nn][d] + yb[d]) * rv[d];
#pragma unroll
    for (int m = 8; m >= 1; m >>= 1) p += __shfl_xor(p, m, 64);
    if (tx == 0) ec[e] = p + cbb;
  }
}

// ---------------- K5: per-edge logits + segment max ----------------
__global__ __launch_bounds__(256) void k5_logits(const float* __restrict__ rel,
                                                 const float* __restrict__ hv,
                                                 const float* __restrict__ J0,
                                                 const float* __restrict__ J1,
                                                 const float* __restrict__ I1,
                                                 const float* __restrict__ wv,
                                                 const float* __restrict__ uv,
                                                 const float* __restrict__ ec,
                                                 const int* __restrict__ node_i,
                                                 const int* __restrict__ node_j,
                                                 float* __restrict__ logits,
                                                 unsigned* __restrict__ segkey) {
  __shared__ float wl[128];
  __shared__ float ul[128];
  int tid = threadIdx.x;
  int e0 = blockIdx.x * 16;
  int b = e0 >> EPQ_SHIFT;
  if (tid < 128) wl[tid] = wv[b * 128 + tid];
  else ul[tid - 128] = uv[b * 128 + (tid - 128)];
  __syncthreads();
  int lane = tid & 15, eg = tid >> 4;
  int e = e0 + eg;
  int i = node_i[e], j = node_j[e];
  int c0 = lane * 8;

  float rr[8], hi[8], hj[8], a0[8], a1[8], ii[8];
  *(float4*)&rr[0] = *(const float4*)&rel[(size_t)e * 128 + c0];
  *(float4*)&rr[4] = *(const float4*)&rel[(size_t)e * 128 + c0 + 4];
  *(float4*)&hi[0] = *(const float4*)&hv[(size_t)i * 128 + c0];
  *(float4*)&hi[4] = *(const float4*)&hv[(size_t)i * 128 + c0 + 4];
  *(float4*)&hj[0] = *(const float4*)&hv[(size_t)j * 128 + c0];
  *(float4*)&hj[4] = *(const float4*)&hv[(size_t)j * 128 + c0 + 4];
  *(float4*)&a0[0] = *(const float4*)&J0[(size_t)j * 128 + c0];
  *(float4*)&a0[4] = *(const float4*)&J0[(size_t)j * 128 + c0 + 4];
  *(float4*)&a1[0] = *(const float4*)&J1[(size_t)j * 128 + c0];
  *(float4*)&a1[4] = *(const float4*)&J1[(size_t)j * 128 + c0 + 4];
  *(float4*)&ii[0] = *(const float4*)&I1[(size_t)i * 128 + c0];
  *(float4*)&ii[4] = *(const float4*)&I1[(size_t)i * 128 + c0 + 4];

  float p = 0.f;
#pragma unroll
  for (int k = 0; k < 8; ++k) {
    p += hi[k] * a0[k];               // hvi . J0[j]
    p += rr[k] * (a1[k] + ii[k]);     // rel . (J1[j] + I1[i])
    p += hi[k] * wl[c0 + k];          // hvi . w_b
    p += hj[k] * ul[c0 + k];          // hvj . u_b
  }
#pragma unroll
  for (int m = 8; m >= 1; m >>= 1) p += __shfl_xor(p, m, 64);
  if (lane == 0) {
    float lg = p + ec[e];
    logits[e] = lg;
    atomicMax(&segkey[i], enc_f(lg));
  }
}

// ---------------- K6: ex = exp(logit - segmax), segment sum ----------------
__global__ void k6_exp(float* __restrict__ exb, const int* __restrict__ node_i,
                       const unsigned* __restrict__ segkey,
                       float* __restrict__ segsum, int E) {
  int e = blockIdx.x * 256 + threadIdx.x;
  if (e >= E) return;
  int i = node_i[e];
  float m = dec_f(segkey[i]);
  float ex = expf(exb[e] - m);
  exb[e] = ex;
  atomicAdd(&segsum[i], ex);
}

// ---------------- K7: per-query exact top-256 radix select + scatter-add ----
__global__ __launch_bounds__(256) void k7_topk(const float* __restrict__ exb,
                                               const int* __restrict__ node_i,
                                               const int* __restrict__ node_j,
                                               const float* __restrict__ segsum,
                                               const float* __restrict__ score,
                                               float* __restrict__ out) {
  __shared__ unsigned vals[2048];
  __shared__ unsigned hist[256];
  __shared__ unsigned sc[256];
  __shared__ unsigned tie_scan[256];
  __shared__ unsigned sel_info[2];
  int q = blockIdx.x, t = threadIdx.x;
  size_t base = (size_t)q * 2048;
#pragma unroll
  for (int l = 0; l < 8; ++l) {
    int el = t * 8 + l;
    int i = node_i[base + el];
    float tgt = exb[base + el] / segsum[i] * score[i];  // attn * src_score >= 0
    vals[el] = __float_as_uint(tgt);
  }
  __syncthreads();
  unsigned prefix = 0, need = KSEL;
  for (int pass = 3; pass >= 0; --pass) {
    hist[t] = 0;
    __syncthreads();
    int sh = pass * 8;
#pragma unroll
    for (int l = 0; l < 8; ++l) {
      unsigned v = vals[t * 8 + l];
      bool match = (pass == 3) || ((v >> (sh + 8)) == (prefix >> (sh + 8)));
      if (match) atomicAdd(&hist[(v >> sh) & 255u], 1u);
    }
    __syncthreads();
    sc[t] = hist[t];
    __syncthreads();
    for (int off = 1; off < 256; off <<= 1) {  // suffix-inclusive sum
      unsigned add = (t + off < 256) ? sc[t + off] : 0u;
      __syncthreads();
      sc[t] += add;
      __syncthreads();
    }
    unsigned above = sc[t] - hist[t];
    if (above < need && need <= sc[t]) {
      sel_info[0] = (unsigned)t;
      sel_info[1] = need - above;
    }
    __syncthreads();
    prefix |= sel_info[0] << sh;
    need = sel_info[1];
    __syncthreads();
  }
  unsigned T = prefix, r = need;
  unsigned lc = 0;
#pragma unroll
  for (int l = 0; l < 8; ++l)
    if (vals[t * 8 + l] == T) lc++;
  tie_scan[t] = lc;
  __syncthreads();
  unsigned own = lc;
  for (int off = 1; off < 256; off <<= 1) {
    unsigned add = (t >= off) ? tie_scan[t - off] : 0u;
    __syncthreads();
    tie_scan[t] += add;
    __syncthreads();
  }
  unsigned excl = tie_scan[t] - own;
  unsigned cnt = 0;
#pragma unroll
  for (int l = 0; l < 8; ++l) {
    int el = t * 8 + l;
    unsigned v = vals[el];
    bool take = false;
    if (v > T) take = true;
    else if (v == T) { if (excl + cnt < r) take = true; cnt++; }
    if (take) {
      int j = node_j[base + el];
      atomicAdd(&out[j], __uint_as_float(v));
    }
  }
}

// ---------------- host ----------------
extern "C" void kernel_launch(void* const* d_in, const int* in_sizes, int n_in,
                              void* d_out, int out_size, void* d_ws, size_t ws_size,
                              hipStream_t stream) {
  const float* score = (const float*)d_in[0];
  const float* hv    = (const float*)d_in[1];
  const float* rel   = (const float*)d_in[2];
  const float* qsrc  = (const float*)d_in[3];
  const float* qrel  = (const float*)d_in[4];
  const float* Wq    = (const float*)d_in[5];
  const float* Wk    = (const float*)d_in[6];
  const int* node_i  = (const int*)d_in[8];
  const int* node_j  = (const int*)d_in[9];

  const int N = in_sizes[0];            // 50000
  const int B = in_sizes[3] / 128;      // 64
  const int E = in_sizes[2] / 128;      // 131072

  float* ws = (float*)d_ws;
  float* M  = ws;
  float* Mt = M + 262144;
  float* J0 = Mt + 262144;
  float* J1 = J0 + (size_t)N * 128;
  float* I1 = J1 + (size_t)N * 128;
  float* wv = I1 + (size_t)N * 128;
  float* uv = wv + (size_t)B * 128;
  float* yv = uv + (size_t)B * 128;
  float* cb = yv + (size_t)B * 128;
  float* ec = cb + B;
  float* exb = ec + E;
  unsigned* segkey = (unsigned*)(exb + E);
  float* segsum = (float*)(segkey + N);
  float* out = (float*)d_out;

  k0_init<<<(N + 255) / 256, 256, 0, stream>>>(out, segsum, segkey, N);
  k1_gemmM<<<dim3(8, 8), 256, 0, stream>>>(Wq, Wk, M, Mt);
  k2v4_proj<<<dim3(3, (N + 127) / 128), 256, 0, stream>>>(hv, M, Mt, J0, J1, I1, N);
  k3_query<<<B, 128, 0, stream>>>(qsrc, qrel, M, Mt, wv, uv, yv, cb);
  k4v4_edgeconst<<<E / 128, 256, 0, stream>>>(rel, M, yv, cb, ec);
  k5_logits<<<E / 16, 256, 0, stream>>>(rel, hv, J0, J1, I1, wv, uv, ec,
                                        node_i, node_j, exb, segkey);
  k6_exp<<<(E + 255) / 256, 256, 0, stream>>>(exb, node_i, segkey, segsum, E);
  k7_topk<<<B, 256, 0, stream>>>(exb, node_i, node_j, segsum, score, out);
}